// Round 1
// baseline (274.836 us; speedup 1.0000x reference)
//
#include <hip/hip_runtime.h>
#include <hip/hip_bf16.h>
#include <math.h>

// Problem: AutoCorrelation (Autoformer). B=16, L=2048, H=8, E=64, fp32.
// Strategy: per-channel FFT (two-real trick, z=q+ik), accumulate S[b,f] =
// sum_{h,e} Qf*conj(Kf); one IFFT per batch -> mean_value[b,d]; top-7 lags
// over batch-mean; per-batch softmax weights; 7-tap weighted circular roll
// of v.

#define B_ 16
#define L_ 2048
#define H_ 8
#define E_ 64
#define C_ (H_ * E_)      // 512 channels per batch
#define NCH (B_ * C_)     // 8192 total channels
#define K_ 7

// ---------- workspace layout ----------
#define Z_OFF   0ull                               // float2[NCH][L] = 134217728 B
#define S_OFF   134217728ull                       // float2[B][L]   = 262144 B
#define MV_OFF  (S_OFF + 262144ull)                // float [B][L]   = 131072 B
#define TK_OFF  (MV_OFF + 131072ull)               // int[7] (pad 64)
#define W_OFF   (TK_OFF + 64ull)                   // float[16][7]

// ---------- kernel T: pack q,k into complex z with [b,h,e][t] layout ----------
__global__ __launch_bounds__(256) void pack_transpose_kernel(
    const float* __restrict__ q, const float* __restrict__ k,
    float2* __restrict__ z) {
  __shared__ float2 tile[32][33];
  int bi = blockIdx.x;
  int te = bi & 1;  bi >>= 1;   // e-tile (0..1)
  int tt = bi & 63; bi >>= 6;   // t-tile (0..63)
  int h  = bi & 7;  bi >>= 3;   // head
  int b  = bi;                  // batch
  int e0 = te * 32, t0 = tt * 32;
  int tx = threadIdx.x, ty = threadIdx.y;
#pragma unroll
  for (int j = 0; j < 4; ++j) {
    int t = t0 + ty + j * 8;
    int e = e0 + tx;
    size_t idx = ((size_t)(b * L_ + t) * H_ + h) * E_ + e;
    tile[ty + j * 8][tx] = make_float2(q[idx], k[idx]);
  }
  __syncthreads();
#pragma unroll
  for (int j = 0; j < 4; ++j) {
    int e = e0 + ty + j * 8;
    int t = t0 + tx;
    size_t o = ((size_t)((b * H_ + h) * E_ + e)) * L_ + t;
    z[o] = tile[tx][ty + j * 8];
  }
}

// ---------- shared FFT helper: radix-2 DIT, N=2048, input bit-reversed ----------
__device__ inline void fft2048(float2* buf, const float2* tw, int tid, int inverse) {
#pragma unroll
  for (int s = 1; s <= 11; ++s) {
    int half = 1 << (s - 1);
    int tws = 11 - s;
    __syncthreads();
#pragma unroll
    for (int r = 0; r < 4; ++r) {
      int j = tid + r * 256;
      int pos = j & (half - 1);
      int i0 = ((j >> (s - 1)) << s) + pos;
      int i1 = i0 + half;
      float2 w = tw[pos << tws];
      float wy = inverse ? -w.y : w.y;
      float2 a = buf[i0], bv = buf[i1];
      float tr = w.x * bv.x - wy * bv.y;
      float ti = w.x * bv.y + wy * bv.x;
      buf[i1] = make_float2(a.x - tr, a.y - ti);
      buf[i0] = make_float2(a.x + tr, a.y + ti);
    }
  }
  __syncthreads();
}

__device__ inline void init_twiddles(float2* tw, int tid) {
  for (int i = tid; i < 1024; i += 256) {
    float ang = -6.2831853071795864769f * (float)i * (1.0f / 2048.0f);
    tw[i] = make_float2(cosf(ang), sinf(ang));
  }
}

// ---------- kernel F: per-channel FFT + freq-domain product accumulation ----------
__global__ __launch_bounds__(256) void fft_corr_kernel(
    const float2* __restrict__ z, float2* __restrict__ S) {
  __shared__ float2 buf[2048];
  __shared__ float2 tw[1024];
  __shared__ float2 sacc[2048];
  int tid = threadIdx.x;
  init_twiddles(tw, tid);
  for (int i = tid; i < 2048; i += 256) sacc[i] = make_float2(0.f, 0.f);

  int cbase = blockIdx.x * 8;       // 8 channels per block, all same batch
  int b = cbase >> 9;               // / 512
  for (int c = 0; c < 8; ++c) {
    const float2* row = z + (size_t)(cbase + c) * L_;
    __syncthreads();                // previous iteration's buf reads done
    for (int i = tid; i < 2048; i += 256) {
      int r = (int)(__brev((unsigned)i) >> 21);
      buf[r] = row[i];
    }
    fft2048(buf, tw, tid, 0);
    // Z = FFT(q + i k). Extract P = Qf * conj(Kf) per frequency.
    for (int i = tid; i < 2048; i += 256) {
      float2 A  = buf[i];
      float2 Bc = buf[(2048 - i) & 2047];
      float rp = 0.5f  * (Bc.x * A.y + Bc.y * A.x);
      float ip = 0.25f * (A.x * A.x + A.y * A.y - Bc.x * Bc.x - Bc.y * Bc.y);
      sacc[i].x += rp;
      sacc[i].y += ip;
    }
  }
  __syncthreads();
  for (int i = tid; i < 2048; i += 256) {
    atomicAdd(&S[b * L_ + i].x, sacc[i].x);
    atomicAdd(&S[b * L_ + i].y, sacc[i].y);
  }
}

// ---------- kernel I: inverse FFT per batch -> mean_value[b][d] ----------
__global__ __launch_bounds__(256) void ifft_kernel(
    const float2* __restrict__ S, float* __restrict__ mv) {
  __shared__ float2 buf[2048];
  __shared__ float2 tw[1024];
  int tid = threadIdx.x;
  int b = blockIdx.x;
  init_twiddles(tw, tid);
  for (int i = tid; i < 2048; i += 256) {
    int r = (int)(__brev((unsigned)i) >> 21);
    buf[r] = S[b * L_ + i];
  }
  fft2048(buf, tw, tid, 1);
  const float scale = 1.0f / (2048.0f * 512.0f);  // irfft 1/N  *  mean over H*E
  for (int i = tid; i < 2048; i += 256) mv[b * L_ + i] = buf[i].x * scale;
}

// ---------- kernel K: batch-mean top-7 + per-batch softmax weights ----------
__global__ __launch_bounds__(256) void topk_kernel(
    const float* __restrict__ mv, int* __restrict__ topk, float* __restrict__ wts) {
  __shared__ float av[2048];
  __shared__ float rv[256];
  __shared__ int   ri[256];
  __shared__ int   sidx[K_];
  int tid = threadIdx.x;
  for (int d = tid; d < 2048; d += 256) {
    float s = 0.f;
#pragma unroll
    for (int b = 0; b < B_; ++b) s += mv[b * L_ + d];
    av[d] = s;   // batch SUM: argmax-equivalent to mean
  }
  __syncthreads();
  for (int k = 0; k < K_; ++k) {
    float bv = -INFINITY; int bi = 0;
    for (int d = tid; d < 2048; d += 256) {
      float vv = av[d];
      if (vv > bv) { bv = vv; bi = d; }   // ascending scan: lowest index on tie
    }
    rv[tid] = bv; ri[tid] = bi;
    __syncthreads();
    for (int off = 128; off > 0; off >>= 1) {
      if (tid < off) {
        float v2 = rv[tid + off]; int i2 = ri[tid + off];
        if (v2 > rv[tid] || (v2 == rv[tid] && i2 < ri[tid])) { rv[tid] = v2; ri[tid] = i2; }
      }
      __syncthreads();
    }
    if (tid == 0) { sidx[k] = ri[0]; av[ri[0]] = -INFINITY; }
    __syncthreads();
  }
  if (tid < K_) topk[tid] = sidx[tid];
  if (tid < B_) {
    float x[K_], m = -INFINITY;
#pragma unroll
    for (int k = 0; k < K_; ++k) { x[k] = mv[tid * L_ + sidx[k]]; m = fmaxf(m, x[k]); }
    float s = 0.f;
#pragma unroll
    for (int k = 0; k < K_; ++k) { x[k] = expf(x[k] - m); s += x[k]; }
#pragma unroll
    for (int k = 0; k < K_; ++k) wts[tid * K_ + k] = x[k] / s;
  }
}

// ---------- kernel G: out[b,t,h,e] = sum_k w[b,k] * v[b,(t+d_k)%L,h,e] ----------
__global__ __launch_bounds__(256) void aggregate_kernel(
    const float4* __restrict__ v4, const int* __restrict__ topk,
    const float* __restrict__ wts, float4* __restrict__ out4) {
  __shared__ int   sidx[K_];
  __shared__ float sw[B_][K_];
  int tid = threadIdx.x;
  if (tid < K_) sidx[tid] = topk[tid];
  if (tid < B_ * K_) sw[tid / K_][tid % K_] = wts[tid];
  __syncthreads();
  int idx = blockIdx.x * 256 + tid;      // 0 .. 4194303 (float4 elements)
  int c4  = idx & 127;                   // (h,e)/4
  int row = idx >> 7;                    // b*L + t
  int t   = row & (L_ - 1);
  int b   = row >> 11;
  float4 acc = make_float4(0.f, 0.f, 0.f, 0.f);
#pragma unroll
  for (int k = 0; k < K_; ++k) {
    int s = t + sidx[k];
    if (s >= L_) s -= L_;
    float w = sw[b][k];
    float4 val = v4[((size_t)(b * L_ + s) << 7) + c4];
    acc.x += w * val.x; acc.y += w * val.y;
    acc.z += w * val.z; acc.w += w * val.w;
  }
  out4[idx] = acc;
}

extern "C" void kernel_launch(void* const* d_in, const int* in_sizes, int n_in,
                              void* d_out, int out_size, void* d_ws, size_t ws_size,
                              hipStream_t stream) {
  const float* q = (const float*)d_in[0];
  const float* k = (const float*)d_in[1];
  const float* v = (const float*)d_in[2];
  float* out = (float*)d_out;

  char* ws = (char*)d_ws;
  float2* z    = (float2*)(ws + Z_OFF);
  float2* S    = (float2*)(ws + S_OFF);
  float*  mv   = (float*) (ws + MV_OFF);
  int*    topk = (int*)   (ws + TK_OFF);
  float*  wts  = (float*) (ws + W_OFF);

  // S is accumulated into via atomics -> must start at zero every call.
  hipMemsetAsync(S, 0, B_ * L_ * sizeof(float2), stream);

  pack_transpose_kernel<<<B_ * H_ * (L_ / 32) * (E_ / 32), dim3(32, 8), 0, stream>>>(q, k, z);
  fft_corr_kernel<<<NCH / 8, 256, 0, stream>>>(z, S);
  ifft_kernel<<<B_, 256, 0, stream>>>(S, mv);
  topk_kernel<<<1, 256, 0, stream>>>(mv, topk, wts);
  aggregate_kernel<<<(B_ * L_ * C_ / 4) / 256, 256, 0, stream>>>(
      (const float4*)v, topk, wts, (float4*)out);
}

// Round 2
// 176.392 us; speedup vs baseline: 1.5581x; 1.5581x over previous
//
#include <hip/hip_runtime.h>
#include <hip/hip_bf16.h>
#include <math.h>

// AutoCorrelation (Autoformer). B=16, L=2048, H=8, E=64, fp32.
// Round 2: radix-8/8/8/4 register FFT (digit-reversed storage end-to-end),
// padded LDS (conflict-free), register accumulators, hoisted twiddles,
// partials+reduce instead of atomics.

#define B_ 16
#define L_ 2048
#define H_ 8
#define E_ 64
#define C_ (H_ * E_)      // 512 channels per batch
#define NCH (B_ * C_)     // 8192
#define K_ 7

// ---------- workspace layout ----------
#define Z_OFF   0ull                               // float2[NCH][L] = 128 MiB (reused for partials)
#define S_OFF   134217728ull                       // float2[B][L] (digit-reversed order)
#define MV_OFF  (S_OFF + 262144ull)                // float [B][L]
#define TK_OFF  (MV_OFF + 131072ull)               // int[7]
#define W_OFF   (TK_OFF + 64ull)                   // float[16][7]

// ---------- complex helpers ----------
__device__ __forceinline__ float2 cadd(float2 a, float2 b) { return make_float2(a.x + b.x, a.y + b.y); }
__device__ __forceinline__ float2 csub(float2 a, float2 b) { return make_float2(a.x - b.x, a.y - b.y); }
__device__ __forceinline__ float2 cmul(float2 a, float2 b) {
  return make_float2(fmaf(a.x, b.x, -a.y * b.y), fmaf(a.x, b.y, a.y * b.x));
}
__device__ __forceinline__ float2 cis(float ang) { float s, c; sincosf(ang, &s, &c); return make_float2(c, s); }

template<int S> __device__ __forceinline__ float2 rot90(float2 z) {  // *W_4^{S}: S=-1 -> -i*z
  return (S < 0) ? make_float2(z.y, -z.x) : make_float2(-z.y, z.x);
}
template<int S> __device__ __forceinline__ void dft4(float2& a, float2& b, float2& c, float2& d) {
  float2 t0 = cadd(a, c), t1 = csub(a, c), t2 = cadd(b, d), t3 = rot90<S>(csub(b, d));
  a = cadd(t0, t2); c = csub(t0, t2); b = cadd(t1, t3); d = csub(t1, t3);
}
template<int S> __device__ __forceinline__ void dft8(float2 v[8]) {
  const float RT = 0.70710678118654752f;
  const float SR = (S < 0) ? -RT : RT;
  float2 a0 = cadd(v[0], v[4]), a1 = cadd(v[1], v[5]), a2 = cadd(v[2], v[6]), a3 = cadd(v[3], v[7]);
  float2 b0 = csub(v[0], v[4]), b1 = csub(v[1], v[5]), b2 = csub(v[2], v[6]), b3 = csub(v[3], v[7]);
  b1 = cmul(b1, make_float2(RT, SR));     // W8^{S}
  b2 = rot90<S>(b2);                      // W8^{2S}
  b3 = cmul(b3, make_float2(-RT, SR));    // W8^{3S}
  dft4<S>(a0, a1, a2, a3);
  dft4<S>(b0, b1, b2, b3);
  v[0] = a0; v[2] = a1; v[4] = a2; v[6] = a3;
  v[1] = b0; v[3] = b1; v[5] = b2; v[7] = b3;
}
// padded LDS index: +1 element per 32 (keeps every stage near the bank floor)
__device__ __forceinline__ int sg(int e) { return e + (e >> 5); }

// ---------- kernel T: pack q,k into complex z with [ch][t] layout ----------
__global__ __launch_bounds__(256) void pack_transpose_kernel(
    const float* __restrict__ q, const float* __restrict__ k,
    float2* __restrict__ z) {
  __shared__ float2 tile[32][33];
  int bi = blockIdx.x;
  int te = bi & 1;  bi >>= 1;
  int tt = bi & 63; bi >>= 6;
  int h  = bi & 7;  bi >>= 3;
  int b  = bi;
  int e0 = te * 32, t0 = tt * 32;
  int tx = threadIdx.x, ty = threadIdx.y;
#pragma unroll
  for (int j = 0; j < 4; ++j) {
    int t = t0 + ty + j * 8;
    int e = e0 + tx;
    size_t idx = ((size_t)(b * L_ + t) * H_ + h) * E_ + e;
    tile[ty + j * 8][tx] = make_float2(q[idx], k[idx]);
  }
  __syncthreads();
#pragma unroll
  for (int j = 0; j < 4; ++j) {
    int e = e0 + ty + j * 8;
    int t = t0 + tx;
    size_t o = ((size_t)((b * H_ + h) * E_ + e)) * L_ + t;
    z[o] = tile[tx][ty + j * 8];
  }
}

// ---------- kernel F: radix-8/8/8/4 DIF FFT + freq product, per-block partials ----------
// Forward DIF: natural input, digit-reversed output p = 256k1+32k2+4k3+k4,
// frequency f(p) = k1 + 8k2 + 64k3 + 512k4.
__global__ __launch_bounds__(256) void fft_corr_kernel(float2* __restrict__ z) {
  __shared__ float2 buf[2112];
  int t = threadIdx.x;
  int j2 = t & 31, j3 = t & 3;
  float2 tw1[7], tw2[7], tw3[7];
#pragma unroll
  for (int k = 1; k <= 7; ++k) {
    tw1[k - 1] = cis(-6.283185307179586f * (float)(t  * k) / 2048.0f);
    tw2[k - 1] = cis(-6.283185307179586f * (float)(j2 * k) / 256.0f);
    tw3[k - 1] = cis(-6.283185307179586f * (float)(j3 * k) / 32.0f);
  }
  float2 acc[8];
#pragma unroll
  for (int k = 0; k < 8; ++k) acc[k] = make_float2(0.f, 0.f);
  int cbase = blockIdx.x * 8;
  int base2 = (t >> 5) * 256 + j2;
  int base3 = (t >> 2) * 32 + j3;

  for (int c = 0; c < 8; ++c) {
    const float2* row = z + (size_t)(cbase + c) * L_;
    float2 v[8];
    // stage 1: M=2048, j=t, elements t+256m (global, coalesced)
#pragma unroll
    for (int m = 0; m < 8; ++m) v[m] = row[t + 256 * m];
    dft8<-1>(v);
#pragma unroll
    for (int k = 1; k < 8; ++k) v[k] = cmul(v[k], tw1[k - 1]);
    __syncthreads();                       // protect prev product-phase reads
#pragma unroll
    for (int k = 0; k < 8; ++k) buf[sg(t + 256 * k)] = v[k];
    __syncthreads();
    // stage 2: M=256
#pragma unroll
    for (int m = 0; m < 8; ++m) v[m] = buf[sg(base2 + 32 * m)];
    dft8<-1>(v);
#pragma unroll
    for (int k = 1; k < 8; ++k) v[k] = cmul(v[k], tw2[k - 1]);
    __syncthreads();
#pragma unroll
    for (int k = 0; k < 8; ++k) buf[sg(base2 + 32 * k)] = v[k];
    __syncthreads();
    // stage 3: M=32
#pragma unroll
    for (int m = 0; m < 8; ++m) v[m] = buf[sg(base3 + 4 * m)];
    dft8<-1>(v);
#pragma unroll
    for (int k = 1; k < 8; ++k) v[k] = cmul(v[k], tw3[k - 1]);
    __syncthreads();
#pragma unroll
    for (int k = 0; k < 8; ++k) buf[sg(base3 + 4 * k)] = v[k];
    __syncthreads();
    // stage 4: M=4 radix-4, positions 8t..8t+7 (thread-private in-place)
    float2 u[8];
#pragma unroll
    for (int k = 0; k < 8; ++k) u[k] = buf[sg(8 * t + k)];
    dft4<-1>(u[0], u[1], u[2], u[3]);
    dft4<-1>(u[4], u[5], u[6], u[7]);
#pragma unroll
    for (int k = 0; k < 8; ++k) buf[sg(8 * t + k)] = u[k];
    __syncthreads();
    // product: P = Qf*conj(Kf) from Z[f], Z[-f] (two-real trick), digit math pairing
#pragma unroll
    for (int k = 0; k < 8; ++k) {
      int p = 8 * t + k;
      int f = ((p >> 8) & 7) | (((p >> 5) & 7) << 3) | (((p >> 2) & 7) << 6) | ((p & 3) << 9);
      int fp = (2048 - f) & 2047;
      int pp = ((fp & 7) << 8) | (((fp >> 3) & 7) << 5) | (((fp >> 6) & 7) << 2) | ((fp >> 9) & 3);
      float2 A = u[k];
      float2 Bc = buf[sg(pp)];
      acc[k].x += 0.5f  * (Bc.x * A.y + Bc.y * A.x);
      acc[k].y += 0.25f * (A.x * A.x + A.y * A.y - Bc.x * Bc.x - Bc.y * Bc.y);
    }
  }
  // transpose acc through LDS so the partial write is coalesced; reuse own z slice
  __syncthreads();
#pragma unroll
  for (int k = 0; k < 8; ++k) buf[sg(8 * t + k)] = acc[k];
  __syncthreads();
  float2* part = z + (size_t)cbase * L_;   // this block's consumed region
#pragma unroll
  for (int m = 0; m < 8; ++m) part[t + 256 * m] = buf[sg(t + 256 * m)];
}

// ---------- kernel R: sum 64 per-block partials -> S[b][p] (storage order) ----------
__global__ __launch_bounds__(256) void reduce_S_kernel(
    const float2* __restrict__ z, float2* __restrict__ S) {
  int gid = blockIdx.x * 256 + threadIdx.x;   // 0..32767
  int b = gid >> 11, p = gid & 2047;
  float2 s = make_float2(0.f, 0.f);
#pragma unroll 4
  for (int i = 0; i < 64; ++i) {
    float2 vv = z[(size_t)((b * 64 + i) * 8) * L_ + p];
    s.x += vv.x; s.y += vv.y;
  }
  S[gid] = s;
}

// ---------- kernel I: mirrored DIT inverse (digit-reversed in, natural out) ----------
__global__ __launch_bounds__(256) void ifft_kernel(
    const float2* __restrict__ S, float* __restrict__ mv) {
  __shared__ float2 buf[2112];
  int t = threadIdx.x, b = blockIdx.x;
  int j2 = t & 31, j3 = t & 3;
  float2 tw1[7], tw2[7], tw3[7];
#pragma unroll
  for (int k = 1; k <= 7; ++k) {
    tw1[k - 1] = cis(6.283185307179586f * (float)(t  * k) / 2048.0f);
    tw2[k - 1] = cis(6.283185307179586f * (float)(j2 * k) / 256.0f);
    tw3[k - 1] = cis(6.283185307179586f * (float)(j3 * k) / 32.0f);
  }
  int base2 = (t >> 5) * 256 + j2;
  int base3 = (t >> 2) * 32 + j3;
  const float2* row = S + b * L_;
  // stage A: M=4 (no twiddle), quads 8t..8t+7
  float2 u[8];
#pragma unroll
  for (int k = 0; k < 8; ++k) u[k] = row[8 * t + k];
  dft4<1>(u[0], u[1], u[2], u[3]);
  dft4<1>(u[4], u[5], u[6], u[7]);
#pragma unroll
  for (int k = 0; k < 8; ++k) buf[sg(8 * t + k)] = u[k];
  __syncthreads();
  // stage B: M=32 (twiddle inputs, then inverse DFT)
  float2 v[8];
#pragma unroll
  for (int k = 0; k < 8; ++k) v[k] = buf[sg(base3 + 4 * k)];
#pragma unroll
  for (int k = 1; k < 8; ++k) v[k] = cmul(v[k], tw3[k - 1]);
  dft8<1>(v);
  __syncthreads();
#pragma unroll
  for (int m = 0; m < 8; ++m) buf[sg(base3 + 4 * m)] = v[m];
  __syncthreads();
  // stage C: M=256
#pragma unroll
  for (int k = 0; k < 8; ++k) v[k] = buf[sg(base2 + 32 * k)];
#pragma unroll
  for (int k = 1; k < 8; ++k) v[k] = cmul(v[k], tw2[k - 1]);
  dft8<1>(v);
  __syncthreads();
#pragma unroll
  for (int m = 0; m < 8; ++m) buf[sg(base2 + 32 * m)] = v[m];
  __syncthreads();
  // stage D: M=2048 -> natural-order x[t+256m] in regs
#pragma unroll
  for (int k = 0; k < 8; ++k) v[k] = buf[sg(t + 256 * k)];
#pragma unroll
  for (int k = 1; k < 8; ++k) v[k] = cmul(v[k], tw1[k - 1]);
  dft8<1>(v);
  const float scale = 1.0f / (2048.0f * 512.0f);  // 1/N * mean over H*E
#pragma unroll
  for (int m = 0; m < 8; ++m) mv[b * L_ + t + 256 * m] = v[m].x * scale;
}

// ---------- kernel K: batch-mean top-7 + per-batch softmax weights ----------
__global__ __launch_bounds__(256) void topk_kernel(
    const float* __restrict__ mv, int* __restrict__ topk, float* __restrict__ wts) {
  __shared__ float av[2048];
  __shared__ float rv[256];
  __shared__ int   ri[256];
  __shared__ int   sidx[K_];
  int tid = threadIdx.x;
  for (int d = tid; d < 2048; d += 256) {
    float s = 0.f;
#pragma unroll
    for (int b = 0; b < B_; ++b) s += mv[b * L_ + d];
    av[d] = s;
  }
  __syncthreads();
  for (int k = 0; k < K_; ++k) {
    float bv = -INFINITY; int bi = 0;
    for (int d = tid; d < 2048; d += 256) {
      float vv = av[d];
      if (vv > bv) { bv = vv; bi = d; }
    }
    rv[tid] = bv; ri[tid] = bi;
    __syncthreads();
    for (int off = 128; off > 0; off >>= 1) {
      if (tid < off) {
        float v2 = rv[tid + off]; int i2 = ri[tid + off];
        if (v2 > rv[tid] || (v2 == rv[tid] && i2 < ri[tid])) { rv[tid] = v2; ri[tid] = i2; }
      }
      __syncthreads();
    }
    if (tid == 0) { sidx[k] = ri[0]; av[ri[0]] = -INFINITY; }
    __syncthreads();
  }
  if (tid < K_) topk[tid] = sidx[tid];
  if (tid < B_) {
    float x[K_], m = -INFINITY;
#pragma unroll
    for (int k = 0; k < K_; ++k) { x[k] = mv[tid * L_ + sidx[k]]; m = fmaxf(m, x[k]); }
    float s = 0.f;
#pragma unroll
    for (int k = 0; k < K_; ++k) { x[k] = expf(x[k] - m); s += x[k]; }
#pragma unroll
    for (int k = 0; k < K_; ++k) wts[tid * K_ + k] = x[k] / s;
  }
}

// ---------- kernel G: out[b,t,h,e] = sum_k w[b,k] * v[b,(t+d_k)%L,h,e] ----------
__global__ __launch_bounds__(256) void aggregate_kernel(
    const float4* __restrict__ v4, const int* __restrict__ topk,
    const float* __restrict__ wts, float4* __restrict__ out4) {
  __shared__ int   sidx[K_];
  __shared__ float sw[B_][K_];
  int tid = threadIdx.x;
  if (tid < K_) sidx[tid] = topk[tid];
  if (tid < B_ * K_) sw[tid / K_][tid % K_] = wts[tid];
  __syncthreads();
  int idx = blockIdx.x * 256 + tid;
  int c4  = idx & 127;
  int row = idx >> 7;
  int t   = row & (L_ - 1);
  int b   = row >> 11;
  float4 acc = make_float4(0.f, 0.f, 0.f, 0.f);
#pragma unroll
  for (int k = 0; k < K_; ++k) {
    int s = t + sidx[k];
    if (s >= L_) s -= L_;
    float w = sw[b][k];
    float4 val = v4[((size_t)(b * L_ + s) << 7) + c4];
    acc.x += w * val.x; acc.y += w * val.y;
    acc.z += w * val.z; acc.w += w * val.w;
  }
  out4[idx] = acc;
}

extern "C" void kernel_launch(void* const* d_in, const int* in_sizes, int n_in,
                              void* d_out, int out_size, void* d_ws, size_t ws_size,
                              hipStream_t stream) {
  const float* q = (const float*)d_in[0];
  const float* k = (const float*)d_in[1];
  const float* v = (const float*)d_in[2];
  float* out = (float*)d_out;

  char* ws = (char*)d_ws;
  float2* z    = (float2*)(ws + Z_OFF);
  float2* S    = (float2*)(ws + S_OFF);
  float*  mv   = (float*) (ws + MV_OFF);
  int*    topk = (int*)   (ws + TK_OFF);
  float*  wts  = (float*) (ws + W_OFF);

  pack_transpose_kernel<<<B_ * H_ * (L_ / 32) * (E_ / 32), dim3(32, 8), 0, stream>>>(q, k, z);
  fft_corr_kernel<<<NCH / 8, 256, 0, stream>>>(z);
  reduce_S_kernel<<<(B_ * L_) / 256, 256, 0, stream>>>(z, S);
  ifft_kernel<<<B_, 256, 0, stream>>>(S, mv);
  topk_kernel<<<1, 256, 0, stream>>>(mv, topk, wts);
  aggregate_kernel<<<(B_ * L_ * C_ / 4) / 256, 256, 0, stream>>>(
      (const float4*)v, topk, wts, (float4*)out);
}